// Round 1
// baseline (1673.979 us; speedup 1.0000x reference)
//
#include <hip/hip_runtime.h>
#include <stdint.h>

// JTMPN on MI355X — round 8: column-sliced XCD-resident gather.
// Theory: gathers are L2-miss-path bound (MSHR x miss-latency ~3.6 TB/s
// beyond-L2), NOT CU-delivery bound (L2 path sustains 56 B/cy/CU). The 75.5MB
// msg table random-accessed against 4MB/XCD L2 gives ~45% hit; all 8 XCDs
// redundantly stream the whole table (470MB FETCH/dispatch vs 75.5MB table).
// Fix: slice HID=512 into 16 x 32-col (64B) slices; XCD x owns slices
// {2x,2x+1}; per slice-phase the slab is 4.7MB ~= L2-resident and each slab is
// fetched by exactly ONE XCD. Indices staged via LDS with nontemporal loads
// (re-read per phase, must not evict slab); nei stores nontemporal (reader is
// a different XCD anyway). Per-element FP summation order unchanged.

#define MAX_NB 15
#define HID 512
#define NA 32768
#define NB 65536
#define NMESS 8192

typedef unsigned short u16;
typedef unsigned int u32;
typedef __bf16 bf16x8 __attribute__((ext_vector_type(8)));
typedef float f32x4 __attribute__((ext_vector_type(4)));
typedef u32 u32x4 __attribute__((ext_vector_type(4)));

__device__ __forceinline__ u16 f2bf(float f) {
  u32 u = __builtin_bit_cast(u32, f);
  u32 r = (u + 0x7fffu + ((u >> 16) & 1u)) >> 16;
  return (u16)r;
}
__device__ __forceinline__ float bf2f(u16 b) {
  u32 u = ((u32)b) << 16;
  return __builtin_bit_cast(float, u);
}
__device__ __forceinline__ float bflo(u32 u) {
  return __builtin_bit_cast(float, u << 16);
}
__device__ __forceinline__ float bfhi(u32 u) {
  return __builtin_bit_cast(float, u & 0xffff0000u);
}

__device__ __forceinline__ void async16(const u16* g, u16* l) {
  __builtin_amdgcn_global_load_lds(
      (const __attribute__((address_space(1))) u32*)g,
      (__attribute__((address_space(3))) u32*)l, 16, 0, 0);
}

// ---------------- prep: fp32 -> bf16 conversions / transposes ----------------
__global__ __launch_bounds__(256) void prep_kernel(
    const float* __restrict__ fbonds, const float* __restrict__ tree,
    const float* __restrict__ Wi, const float* __restrict__ Wh,
    const float* __restrict__ Wo, u16* __restrict__ msg,
    u16* __restrict__ fbpad, u16* __restrict__ wi_t, u16* __restrict__ wh_t,
    u16* __restrict__ wo_t) {
  int t = blockIdx.x * 256 + threadIdx.x;
  const int N0 = NMESS * HID;  // 4194304
  const int N1 = NB * 64;      // 4194304
  const int N2 = 512 * 64;
  const int N3 = 512 * 512;
  const int N4 = 512 * 576;
  if (t < N0) { msg[t] = f2bf(tree[t]); return; }
  t -= N0;
  if (t < N1) {
    int row = t >> 6, c = t & 63;
    fbpad[t] = (c < 40) ? f2bf(fbonds[row * 40 + c]) : (u16)0;
    return;
  }
  t -= N1;
  if (t < N2) {
    int n = t >> 6, k = t & 63;
    wi_t[t] = (k < 40) ? f2bf(Wi[k * 512 + n]) : (u16)0;
    return;
  }
  t -= N2;
  if (t < N3) {
    int n = t >> 9, k = t & 511;
    wh_t[t] = f2bf(Wh[k * 512 + n]);
    return;
  }
  t -= N3;
  if (t < N4) {
    int n = t / 576, k = t - n * 576;
    float v = 0.f;
    if (k < 512) v = Wo[(35 + k) * 512 + n];        // nei part
    else if (k < 547) v = Wo[(k - 512) * 512 + n];  // fatoms part
    wo_t[t] = f2bf(v);
    return;
  }
}

// ---------------- sliced gather-sum (bonds) ----------------
// Grid 16384 blocks: L&7 = xcd, q = L>>3 in [0,2048).
// slice = 2*xcd + (q>>10) in [0,16); chunk = q&1023 -> 64 rows/block.
// Wave: 16 rows x 4 lanes; each lane covers 8 cols (16B) of the 32-col slice.
__global__ __launch_bounds__(256) void gather_bonds(
    const u16* __restrict__ msg, const int* __restrict__ bgraph,
    u16* __restrict__ nei) {
  __shared__ int sidx[64 * MAX_NB];
  const int L = blockIdx.x;
  const int xcd = L & 7;
  const int q = L >> 3;
  const int slice = 2 * xcd + (q >> 10);
  const int chunk = q & 1023;
  const int t = threadIdx.x;

  const int* gb = bgraph + chunk * (64 * MAX_NB);
  for (int i = t; i < 64 * MAX_NB; i += 256)
    sidx[i] = __builtin_nontemporal_load(gb + i);
  __syncthreads();

  const int lane = t & 63;
  const int w = t >> 6;
  const int rl = w * 16 + (lane >> 2);  // row within block [0,64)
  const int sub = lane & 3;
  const int row = chunk * 64 + rl;
  const int colOff = slice * 32 + sub * 8;  // element offset in the row

  int ids[MAX_NB];
#pragma unroll
  for (int j = 0; j < MAX_NB; j++) ids[j] = sidx[rl * MAX_NB + j];

  float acc[8] = {0, 0, 0, 0, 0, 0, 0, 0};
#pragma unroll
  for (int j = 0; j < MAX_NB; j++) {
    uint4 v = *(const uint4*)(msg + (size_t)ids[j] * HID + colOff);
    acc[0] += bflo(v.x); acc[1] += bfhi(v.x);
    acc[2] += bflo(v.y); acc[3] += bfhi(v.y);
    acc[4] += bflo(v.z); acc[5] += bfhi(v.z);
    acc[6] += bflo(v.w); acc[7] += bfhi(v.w);
  }
  u32x4 o;
  o.x = (u32)f2bf(acc[0]) | ((u32)f2bf(acc[1]) << 16);
  o.y = (u32)f2bf(acc[2]) | ((u32)f2bf(acc[3]) << 16);
  o.z = (u32)f2bf(acc[4]) | ((u32)f2bf(acc[5]) << 16);
  o.w = (u32)f2bf(acc[6]) | ((u32)f2bf(acc[7]) << 16);
  __builtin_nontemporal_store(o, (u32x4*)(nei + (size_t)row * HID + colOff));
}

// ---------------- sliced gather-sum (atoms) ----------------
// Grid 8192 blocks: q = L>>3 in [0,1024); slice = 2*xcd + (q>>9); chunk=q&511.
// ainput row stride 576 = [nei(512) | fatoms(35)+pad(29)]; tail written once
// by xcd==0 phase-0 blocks.
__global__ __launch_bounds__(256) void gather_atoms(
    const u16* __restrict__ msg, const int* __restrict__ agraph,
    const float* __restrict__ fatoms, u16* __restrict__ ainput) {
  __shared__ int sidx[64 * MAX_NB];
  const int L = blockIdx.x;
  const int xcd = L & 7;
  const int q = L >> 3;
  const int sl = q >> 9;
  const int slice = 2 * xcd + sl;
  const int chunk = q & 511;
  const int t = threadIdx.x;

  const int* ga = agraph + chunk * (64 * MAX_NB);
  for (int i = t; i < 64 * MAX_NB; i += 256)
    sidx[i] = __builtin_nontemporal_load(ga + i);
  __syncthreads();

  const int lane = t & 63;
  const int w = t >> 6;
  const int rl = w * 16 + (lane >> 2);
  const int sub = lane & 3;
  const int row = chunk * 64 + rl;
  const int colOff = slice * 32 + sub * 8;

  int ids[MAX_NB];
#pragma unroll
  for (int j = 0; j < MAX_NB; j++) ids[j] = sidx[rl * MAX_NB + j];

  float acc[8] = {0, 0, 0, 0, 0, 0, 0, 0};
#pragma unroll
  for (int j = 0; j < MAX_NB; j++) {
    uint4 v = *(const uint4*)(msg + (size_t)ids[j] * HID + colOff);
    acc[0] += bflo(v.x); acc[1] += bfhi(v.x);
    acc[2] += bflo(v.y); acc[3] += bfhi(v.y);
    acc[4] += bflo(v.z); acc[5] += bfhi(v.z);
    acc[6] += bflo(v.w); acc[7] += bfhi(v.w);
  }
  u16* arow = ainput + (size_t)row * 576;
  u32x4 o;
  o.x = (u32)f2bf(acc[0]) | ((u32)f2bf(acc[1]) << 16);
  o.y = (u32)f2bf(acc[2]) | ((u32)f2bf(acc[3]) << 16);
  o.z = (u32)f2bf(acc[4]) | ((u32)f2bf(acc[5]) << 16);
  o.w = (u32)f2bf(acc[6]) | ((u32)f2bf(acc[7]) << 16);
  __builtin_nontemporal_store(o, (u32x4*)(arow + colOff));

  if (xcd == 0 && sl == 0) {
    // fatoms tail: cols [512+sub*16, 512+sub*16+16)
    u32 tw[8];
#pragma unroll
    for (int c = 0; c < 8; c++) {
      int c0 = sub * 16 + 2 * c;
      float a = (c0 < 35) ? fatoms[(size_t)row * 35 + c0] : 0.f;
      float b = (c0 + 1 < 35) ? fatoms[(size_t)row * 35 + c0 + 1] : 0.f;
      tw[c] = (u32)f2bf(a) | ((u32)f2bf(b) << 16);
    }
    uint4* tp = (uint4*)(arow + 512 + sub * 16);
    tp[0] = make_uint4(tw[0], tw[1], tw[2], tw[3]);
    tp[1] = make_uint4(tw[4], tw[5], tw[6], tw[7]);
  }
}

// ---------------- 128x128 bf16 MFMA GEMM, XCD-swizzled 1D grid ---------------
// EPI 0: binput=acc, msg=relu(acc);  EPI 1: msg=relu(acc+binput);
// EPI 2: out[mol] = mean(relu(acc+bias))
template <int EPI>
__global__ __launch_bounds__(256) void gemm_k(
    const u16* __restrict__ A, const u16* __restrict__ Bt, int K, int mtx,
    u16* __restrict__ binput, u16* __restrict__ msgout,
    const float* __restrict__ bo, const int* __restrict__ scope,
    float* __restrict__ out) {
  __shared__ __align__(16) u16 As[128 * 32];
  __shared__ __align__(16) u16 Bs[128 * 32];
  const int L = blockIdx.x;
  const int xcd = L & 7;
  const int q = L >> 3;
  const int mBase = (xcd * mtx + (q >> 2)) * 128;
  const int nBase = (q & 3) * 128;
  const int t = threadIdx.x;
  const int lane = t & 63;
  const int w = t >> 6;
  const int wm = w & 1, wn = w >> 1;
  const int r = t >> 2;
  const int c8 = (t & 3) * 8;
  const int q8 = (lane >> 4) * 8;
  const int l15 = lane & 15;

  f32x4 acc[4][4];
#pragma unroll
  for (int i = 0; i < 4; i++)
#pragma unroll
    for (int j = 0; j < 4; j++)
#pragma unroll
      for (int rg = 0; rg < 4; rg++) acc[i][j][rg] = 0.f;

  for (int kb = 0; kb < K; kb += 32) {
    __syncthreads();
    async16(A + (size_t)(mBase + r) * K + kb + c8, As + r * 32 + c8);
    async16(A + (size_t)(mBase + r + 64) * K + kb + c8, As + (r + 64) * 32 + c8);
    async16(Bt + (size_t)(nBase + r) * K + kb + c8, Bs + r * 32 + c8);
    async16(Bt + (size_t)(nBase + r + 64) * K + kb + c8, Bs + (r + 64) * 32 + c8);
    __syncthreads();
    bf16x8 av[4], bv[4];
#pragma unroll
    for (int i = 0; i < 4; i++)
      av[i] = *(const bf16x8*)(As + (wm * 64 + i * 16 + l15) * 32 + q8);
#pragma unroll
    for (int j = 0; j < 4; j++)
      bv[j] = *(const bf16x8*)(Bs + (wn * 64 + j * 16 + l15) * 32 + q8);
#pragma unroll
    for (int i = 0; i < 4; i++)
#pragma unroll
      for (int j = 0; j < 4; j++)
        acc[i][j] = __builtin_amdgcn_mfma_f32_16x16x32_bf16(av[i], bv[j],
                                                            acc[i][j], 0, 0, 0);
  }

  if (EPI == 2) {
#pragma unroll
    for (int m = 0; m < 2; m++) {
      int mol = (mBase + wm * 64 + m * 32) >> 5;
      float inv_le = 1.0f / (float)scope[mol * 2 + 1];
#pragma unroll
      for (int j = 0; j < 4; j++) {
        int col = nBase + wn * 64 + j * 16 + l15;
        float bias = bo[col];
        float s = 0.f;
#pragma unroll
        for (int i = 2 * m; i < 2 * m + 2; i++)
#pragma unroll
          for (int rg = 0; rg < 4; rg++)
            s += fmaxf(acc[i][j][rg] + bias, 0.f);
        s += __shfl_xor(s, 16, 64);
        s += __shfl_xor(s, 32, 64);
        if (lane < 16) out[(size_t)mol * HID + col] = s * inv_le;
      }
    }
  } else {
#pragma unroll
    for (int i = 0; i < 4; i++) {
      int row = mBase + wm * 64 + i * 16 + (lane >> 4) * 4;
#pragma unroll
      for (int j = 0; j < 4; j++) {
        int col = nBase + wn * 64 + j * 16 + l15;
#pragma unroll
        for (int rg = 0; rg < 4; rg++) {
          float v = acc[i][j][rg];
          size_t gi = (size_t)(row + rg) * HID + col;
          if (EPI == 0) {
            binput[gi] = f2bf(v);
            msgout[gi + (size_t)NMESS * HID] = f2bf(fmaxf(v, 0.f));
          } else {
            v += bf2f(binput[gi]);
            msgout[gi + (size_t)NMESS * HID] = f2bf(fmaxf(v, 0.f));
          }
        }
      }
    }
  }
}

// ---------------- launch ----------------
extern "C" void kernel_launch(void* const* d_in, const int* in_sizes, int n_in,
                              void* d_out, int out_size, void* d_ws,
                              size_t ws_size, hipStream_t stream) {
  const float* fatoms = (const float*)d_in[0];
  const float* fbonds = (const float*)d_in[1];
  const int* agraph = (const int*)d_in[2];
  const int* bgraph = (const int*)d_in[3];
  const int* scope = (const int*)d_in[4];
  const float* tree = (const float*)d_in[5];
  const float* Wi = (const float*)d_in[6];
  const float* Wh = (const float*)d_in[7];
  const float* Wo = (const float*)d_in[8];
  const float* bo = (const float*)d_in[9];
  float* out = (float*)d_out;

  char* ws = (char*)d_ws;
  u16* msg = (u16*)(ws);
  u16* binput = (u16*)(ws + 75497472ull);
  u16* nei = (u16*)(ws + 142606336ull);
  u16* wi_t = (u16*)(ws + 209715200ull);
  u16* wh_t = (u16*)(ws + 209780736ull);
  u16* wo_t = (u16*)(ws + 210305024ull);
  u16* fbpad = nei;     // alias: fbpad dead before first gather writes nei
  u16* ainput = binput; // alias: binput dead after last EPI=1 gemm

  prep_kernel<<<35072, 256, 0, stream>>>(fbonds, tree, Wi, Wh, Wo, msg, fbpad,
                                         wi_t, wh_t, wo_t);

  // init: M=65536 -> 512 mtiles, 64 per XCD
  gemm_k<0><<<2048, 256, 0, stream>>>(fbpad, wi_t, 64, 64, binput, msg,
                                      nullptr, nullptr, nullptr);
  for (int d = 0; d < 5; d++) {
    gather_bonds<<<16384, 256, 0, stream>>>(msg, bgraph, nei);
    gemm_k<1><<<2048, 256, 0, stream>>>(nei, wh_t, 512, 64, binput, msg,
                                        nullptr, nullptr, nullptr);
  }
  gather_atoms<<<8192, 256, 0, stream>>>(msg, agraph, fatoms, ainput);
  // out: M=32768 -> 256 mtiles, 32 per XCD
  gemm_k<2><<<1024, 256, 0, stream>>>(ainput, wo_t, 576, 32, nullptr, nullptr,
                                      bo, scope, out);
}

// Round 2
// 1512.782 us; speedup vs baseline: 1.1066x; 1.1066x over previous
//
#include <hip/hip_runtime.h>
#include <stdint.h>

// JTMPN on MI355X — round 9: gather fused into consuming GEMM.
// r8 lesson: 64B column slices double compulsory fetch (128B L2 lines) and
// MALL residency cannot be engineered -> reverted. The gather is delivery-
// latency-bound (~10.5 B/cy/CU, VALU 18%, Mfma 0) and its byte demand is
// irreducible at bf16. r9 instead removes everything serialized around it:
// each block gathers its 32-row A-tile into LDS (identical f2bf numerics),
// runs MFMA vs L2-resident Wh directly, and writes relu(binput+acc) as the
// next message table. GEMM time + nei round-trip (65MB write + re-read)
// disappear under the delivery-bound gather. Message table ping-pongs only
// the graph part (tree rows shared) -> exact r7 workspace footprint.

#define MAX_NB 15
#define HID 512
#define NA 32768
#define NB 65536
#define NMESS 8192
#define GAPE 33554432u  // (graphB - graphA) in elements = 64MB/2

typedef unsigned short u16;
typedef unsigned int u32;
typedef __bf16 bf16x8 __attribute__((ext_vector_type(8)));
typedef float f32x4 __attribute__((ext_vector_type(4)));

__device__ __forceinline__ u16 f2bf(float f) {
  u32 u = __builtin_bit_cast(u32, f);
  u32 r = (u + 0x7fffu + ((u >> 16) & 1u)) >> 16;
  return (u16)r;
}
__device__ __forceinline__ float bf2f(u16 b) {
  u32 u = ((u32)b) << 16;
  return __builtin_bit_cast(float, u);
}
__device__ __forceinline__ float bflo(u32 u) {
  return __builtin_bit_cast(float, u << 16);
}
__device__ __forceinline__ float bfhi(u32 u) {
  return __builtin_bit_cast(float, u & 0xffff0000u);
}

__device__ __forceinline__ void async16(const u16* g, u16* l) {
  __builtin_amdgcn_global_load_lds(
      (const __attribute__((address_space(1))) u32*)g,
      (__attribute__((address_space(3))) u32*)l, 16, 0, 0);
}

// ---------------- prep: fp32 -> bf16 conversions / transposes ----------------
__global__ __launch_bounds__(256) void prep_kernel(
    const float* __restrict__ fbonds, const float* __restrict__ tree,
    const float* __restrict__ Wi, const float* __restrict__ Wh,
    const float* __restrict__ Wo, u16* __restrict__ tab,
    u16* __restrict__ fbpad, u16* __restrict__ wi_t, u16* __restrict__ wh_t,
    u16* __restrict__ wo_t) {
  int t = blockIdx.x * 256 + threadIdx.x;
  const int N0 = NMESS * HID;  // 4194304 (tree rows, shared by both parities)
  const int N1 = NB * 64;      // 4194304
  const int N2 = 512 * 64;
  const int N3 = 512 * 512;
  const int N4 = 512 * 576;
  if (t < N0) { tab[t] = f2bf(tree[t]); return; }
  t -= N0;
  if (t < N1) {
    int row = t >> 6, c = t & 63;
    fbpad[t] = (c < 40) ? f2bf(fbonds[row * 40 + c]) : (u16)0;
    return;
  }
  t -= N1;
  if (t < N2) {
    int n = t >> 6, k = t & 63;
    wi_t[t] = (k < 40) ? f2bf(Wi[k * 512 + n]) : (u16)0;
    return;
  }
  t -= N2;
  if (t < N3) {
    int n = t >> 9, k = t & 511;
    wh_t[t] = f2bf(Wh[k * 512 + n]);
    return;
  }
  t -= N3;
  if (t < N4) {
    int n = t / 576, k = t - n * 576;
    float v = 0.f;
    if (k < 512) v = Wo[(35 + k) * 512 + n];        // nei part
    else if (k < 547) v = Wo[(k - 512) * 512 + n];  // fatoms part
    wo_t[t] = f2bf(v);
    return;
  }
}

// ---------------- init GEMM: binput = fbpad@Wi, graphA = relu(binput) -------
// 128x128 tiles, K=64, XCD-swizzled 1D grid (r7-proven structure).
__global__ __launch_bounds__(256) void gemm_init(
    const u16* __restrict__ A, const u16* __restrict__ Bt,
    u16* __restrict__ binput, u16* __restrict__ graphA) {
  const int K = 64;
  __shared__ __align__(16) u16 As[128 * 32];
  __shared__ __align__(16) u16 Bs[128 * 32];
  const int L = blockIdx.x;
  const int xcd = L & 7;
  const int q = L >> 3;
  const int mBase = (xcd * 64 + (q >> 2)) * 128;
  const int nBase = (q & 3) * 128;
  const int t = threadIdx.x;
  const int lane = t & 63;
  const int w = t >> 6;
  const int wm = w & 1, wn = w >> 1;
  const int r = t >> 2;
  const int c8 = (t & 3) * 8;
  const int q8 = (lane >> 4) * 8;
  const int l15 = lane & 15;

  f32x4 acc[4][4];
#pragma unroll
  for (int i = 0; i < 4; i++)
#pragma unroll
    for (int j = 0; j < 4; j++)
#pragma unroll
      for (int rg = 0; rg < 4; rg++) acc[i][j][rg] = 0.f;

  for (int kb = 0; kb < K; kb += 32) {
    __syncthreads();
    async16(A + (size_t)(mBase + r) * K + kb + c8, As + r * 32 + c8);
    async16(A + (size_t)(mBase + r + 64) * K + kb + c8, As + (r + 64) * 32 + c8);
    async16(Bt + (size_t)(nBase + r) * K + kb + c8, Bs + r * 32 + c8);
    async16(Bt + (size_t)(nBase + r + 64) * K + kb + c8, Bs + (r + 64) * 32 + c8);
    __syncthreads();
    bf16x8 av[4], bv[4];
#pragma unroll
    for (int i = 0; i < 4; i++)
      av[i] = *(const bf16x8*)(As + (wm * 64 + i * 16 + l15) * 32 + q8);
#pragma unroll
    for (int j = 0; j < 4; j++)
      bv[j] = *(const bf16x8*)(Bs + (wn * 64 + j * 16 + l15) * 32 + q8);
#pragma unroll
    for (int i = 0; i < 4; i++)
#pragma unroll
      for (int j = 0; j < 4; j++)
        acc[i][j] = __builtin_amdgcn_mfma_f32_16x16x32_bf16(av[i], bv[j],
                                                            acc[i][j], 0, 0, 0);
  }

#pragma unroll
  for (int i = 0; i < 4; i++) {
    int row = mBase + wm * 64 + i * 16 + (lane >> 4) * 4;
#pragma unroll
    for (int j = 0; j < 4; j++) {
      int col = nBase + wn * 64 + j * 16 + l15;
#pragma unroll
      for (int rg = 0; rg < 4; rg++) {
        float v = acc[i][j][rg];
        size_t gi = (size_t)(row + rg) * HID + col;
        binput[gi] = f2bf(v);
        graphA[gi] = f2bf(fmaxf(v, 0.f));
      }
    }
  }
}

// ---------------- fused gather + GEMM --------------------------------------
// Block = 32 rows x full N=512. Phase 1: 4 waves gather 8 rows each from the
// message table (wave-uniform ids; same f2bf rounding as the standalone
// gather), pack to bf16 LDS k-tiles [NT][32r][32k]. Phase 2: each wave MFMAs
// its 128-col quarter against Bt read direct-to-reg (L2-resident weights).
// ATOMS=0: epilogue relu(binput+acc) -> outGraph. ATOMS=1: K=576 (fatoms
// tail in k-tiles 16,17), epilogue per-molecule mean (block == 1 molecule).
template <int ATOMS>
__global__ __launch_bounds__(256, 3) void fused_gg(
    const u16* __restrict__ tab, const int* __restrict__ graph,
    const u16* __restrict__ Bt, const u16* __restrict__ binput,
    const float* __restrict__ fatoms, const float* __restrict__ bo,
    const int* __restrict__ scope, u16* __restrict__ outGraph,
    float* __restrict__ out, u32 gap) {
  constexpr int K = ATOMS ? 576 : 512;
  constexpr int NT = K / 32;
  __shared__ __align__(16) u16 As[NT * 1024];
  __shared__ int sidx[32 * MAX_NB];
  const int mBase = blockIdx.x * 32;
  const int t = threadIdx.x;
  for (int i = t; i < 32 * MAX_NB; i += 256)
    sidx[i] = graph[mBase * MAX_NB + i];
  __syncthreads();

  const int lane = t & 63;
  const int w = t >> 6;
  // ---- gather phase: wave w owns rows w*8 .. w*8+7 ----
  for (int r = 0; r < 8; r++) {
    const int rl = w * 8 + r;
    float acc[8] = {0, 0, 0, 0, 0, 0, 0, 0};
#pragma unroll
    for (int j = 0; j < MAX_NB; j++) {
      int id = sidx[rl * MAX_NB + j];
      u32 off = (u32)id * HID + (id >= NMESS ? gap : 0u);
      uint4 v = *(const uint4*)(tab + off + lane * 8);
      acc[0] += bflo(v.x); acc[1] += bfhi(v.x);
      acc[2] += bflo(v.y); acc[3] += bfhi(v.y);
      acc[4] += bflo(v.z); acc[5] += bfhi(v.z);
      acc[6] += bflo(v.w); acc[7] += bfhi(v.w);
    }
    uint4 o;
    o.x = (u32)f2bf(acc[0]) | ((u32)f2bf(acc[1]) << 16);
    o.y = (u32)f2bf(acc[2]) | ((u32)f2bf(acc[3]) << 16);
    o.z = (u32)f2bf(acc[4]) | ((u32)f2bf(acc[5]) << 16);
    o.w = (u32)f2bf(acc[6]) | ((u32)f2bf(acc[7]) << 16);
    // k-tiled LDS: tile = lane>>2, within-tile chunk = lane&3
    *(uint4*)(As + (lane >> 2) * 1024 + rl * 32 + (lane & 3) * 8) = o;
    if (ATOMS) {
      if (lane < 8) {  // fatoms tail: cols 512..575 (k-tiles 16,17)
        u32 tw[4];
#pragma unroll
        for (int c = 0; c < 4; c++) {
          int c0 = lane * 8 + 2 * c;
          float a = (c0 < 35) ? fatoms[(size_t)(mBase + rl) * 35 + c0] : 0.f;
          float b =
              (c0 + 1 < 35) ? fatoms[(size_t)(mBase + rl) * 35 + c0 + 1] : 0.f;
          tw[c] = (u32)f2bf(a) | ((u32)f2bf(b) << 16);
        }
        *(uint4*)(As + (16 + (lane >> 2)) * 1024 + rl * 32 + (lane & 3) * 8) =
            make_uint4(tw[0], tw[1], tw[2], tw[3]);
      }
    }
  }
  __syncthreads();

  // ---- GEMM phase: wave w = n-quarter, rows 0..31, K full ----
  const int l15 = lane & 15;
  const int q8 = (lane >> 4) * 8;
  const int nq = w;
  f32x4 acc2[2][8];
#pragma unroll
  for (int i = 0; i < 2; i++)
#pragma unroll
    for (int j = 0; j < 8; j++)
#pragma unroll
      for (int rg = 0; rg < 4; rg++) acc2[i][j][rg] = 0.f;

  for (int kbi = 0; kbi < NT; kbi++) {
    bf16x8 av0 = *(const bf16x8*)(As + kbi * 1024 + l15 * 32 + q8);
    bf16x8 av1 = *(const bf16x8*)(As + kbi * 1024 + (16 + l15) * 32 + q8);
    bf16x8 bv[8];
#pragma unroll
    for (int j = 0; j < 8; j++)
      bv[j] = *(const bf16x8*)(Bt + (size_t)(nq * 128 + j * 16 + l15) * K +
                               kbi * 32 + q8);
#pragma unroll
    for (int j = 0; j < 8; j++) {
      acc2[0][j] =
          __builtin_amdgcn_mfma_f32_16x16x32_bf16(av0, bv[j], acc2[0][j], 0, 0, 0);
      acc2[1][j] =
          __builtin_amdgcn_mfma_f32_16x16x32_bf16(av1, bv[j], acc2[1][j], 0, 0, 0);
    }
  }

  if (ATOMS) {
    const int mol = blockIdx.x;  // 32 rows == exactly one molecule
    float inv = 1.0f / (float)scope[mol * 2 + 1];
#pragma unroll
    for (int j = 0; j < 8; j++) {
      int col = nq * 128 + j * 16 + l15;
      float bias = bo[col];
      float s = 0.f;
#pragma unroll
      for (int i = 0; i < 2; i++)
#pragma unroll
        for (int rg = 0; rg < 4; rg++)
          s += fmaxf(acc2[i][j][rg] + bias, 0.f);
      s += __shfl_xor(s, 16, 64);
      s += __shfl_xor(s, 32, 64);
      if (lane < 16) out[(size_t)mol * HID + col] = s * inv;
    }
  } else {
#pragma unroll
    for (int i = 0; i < 2; i++) {
      int row = mBase + i * 16 + (lane >> 4) * 4;
#pragma unroll
      for (int j = 0; j < 8; j++) {
        int col = nq * 128 + j * 16 + l15;
#pragma unroll
        for (int rg = 0; rg < 4; rg++) {
          size_t gi = (size_t)(row + rg) * HID + col;
          float v = acc2[i][j][rg] + bf2f(binput[gi]);
          outGraph[gi] = f2bf(fmaxf(v, 0.f));
        }
      }
    }
  }
}

// ---------------- launch ----------------
extern "C" void kernel_launch(void* const* d_in, const int* in_sizes, int n_in,
                              void* d_out, int out_size, void* d_ws,
                              size_t ws_size, hipStream_t stream) {
  const float* fatoms = (const float*)d_in[0];
  const float* fbonds = (const float*)d_in[1];
  const int* agraph = (const int*)d_in[2];
  const int* bgraph = (const int*)d_in[3];
  const int* scope = (const int*)d_in[4];
  const float* tree = (const float*)d_in[5];
  const float* Wi = (const float*)d_in[6];
  const float* Wh = (const float*)d_in[7];
  const float* Wo = (const float*)d_in[8];
  const float* bo = (const float*)d_in[9];
  float* out = (float*)d_out;

  // layout (exact r7 footprint 210,894,848 B):
  // [tree 8.4MB][graphA 67MB][graphB 67MB][binput 67MB][wi|wh|wo 1.2MB]
  u16* tab = (u16*)d_ws;                          // tree rows 0..8191
  u16* graphA = tab + (size_t)NMESS * HID;        // @ 8,388,608
  u16* graphB = graphA + (size_t)NB * HID;        // @ 75,497,472
  u16* binput = graphB + (size_t)NB * HID;        // @ 142,606,336
  u16* wi_t = binput + (size_t)NB * HID;          // @ 209,715,200
  u16* wh_t = wi_t + 512 * 64;
  u16* wo_t = wh_t + 512 * 512;
  u16* fbpad = graphB;  // alias: dead before fused d=0 writes graphB

  prep_kernel<<<35072, 256, 0, stream>>>(fbonds, tree, Wi, Wh, Wo, tab, fbpad,
                                         wi_t, wh_t, wo_t);

  gemm_init<<<2048, 256, 0, stream>>>(fbpad, wi_t, binput, graphA);

  // ping-pong graph part; tree rows shared (id<NMESS -> gap 0 both parities)
  const u32 gaps[5] = {0u, GAPE, 0u, GAPE, 0u};
  u16* const outs[5] = {graphB, graphA, graphB, graphA, graphB};
  for (int d = 0; d < 5; d++) {
    fused_gg<0><<<2048, 256, 0, stream>>>(tab, bgraph, wh_t, binput, nullptr,
                                          nullptr, nullptr, outs[d], nullptr,
                                          gaps[d]);
  }
  // final: read graphB (gap=GAPE), one molecule per block
  fused_gg<1><<<1024, 256, 0, stream>>>(tab, agraph, wo_t, nullptr, fatoms, bo,
                                        scope, nullptr, out, GAPE);
}

// Round 3
// 1242.909 us; speedup vs baseline: 1.3468x; 1.2171x over previous
//
#include <hip/hip_runtime.h>
#include <stdint.h>

// JTMPN on MI355X — round 10: augmented-K GEMM, binput eliminated.
// Walls calibrated from r7/r9: miss-path (L2<->MALL) ~3.6 TB/s, CU-delivery
// ~8 TB/s. Gather sits on the miss wall and its bytes are irreducible
// (uniform-random indices). r9 fusion lost on B re-delivery (1 GB/iter).
// r10: relu(binput + nei@Wh) == relu([fbpad|nei] @ [[Wi];[Wh]]) -> K=576
// GEMM reading fbpad (8.4MB, L2-hot) instead of binput (67MB miss) each
// iteration; binput buffer, its init write, and epilogue re-read all deleted.
// Gathers + GEMM structure are the r7-verified code verbatim.

#define MAX_NB 15
#define HID 512
#define NA 32768
#define NB 65536
#define NMESS 8192

typedef unsigned short u16;
typedef unsigned int u32;
typedef __bf16 bf16x8 __attribute__((ext_vector_type(8)));
typedef float f32x4 __attribute__((ext_vector_type(4)));

__device__ __forceinline__ u16 f2bf(float f) {
  u32 u = __builtin_bit_cast(u32, f);
  u32 r = (u + 0x7fffu + ((u >> 16) & 1u)) >> 16;
  return (u16)r;
}
__device__ __forceinline__ float bflo(u32 u) {
  return __builtin_bit_cast(float, u << 16);
}
__device__ __forceinline__ float bfhi(u32 u) {
  return __builtin_bit_cast(float, u & 0xffff0000u);
}

__device__ __forceinline__ void async16(const u16* g, u16* l) {
  __builtin_amdgcn_global_load_lds(
      (const __attribute__((address_space(1))) u32*)g,
      (__attribute__((address_space(3))) u32*)l, 16, 0, 0);
}

// ---------------- prep: fp32 -> bf16 conversions / transposes ----------------
// wcat[n][k], k in [0,576): k<40 -> Wi[k][n]; 40<=k<64 -> 0 (fbpad pad);
// k>=64 -> Wh[k-64][n]. wo_t[n][k]: k<512 -> Wo[35+k][n]; k<547 -> Wo[k-512][n].
__global__ __launch_bounds__(256) void prep_kernel(
    const float* __restrict__ fbonds, const float* __restrict__ tree,
    const float* __restrict__ Wi, const float* __restrict__ Wh,
    const float* __restrict__ Wo, u16* __restrict__ msg,
    u16* __restrict__ fbpad, u16* __restrict__ wcat, u16* __restrict__ wo_t) {
  int t = blockIdx.x * 256 + threadIdx.x;
  const int N0 = NMESS * HID;  // 4194304
  const int N1 = NB * 64;      // 4194304
  const int N2 = 512 * 576;    // 294912
  const int N3 = 512 * 576;    // 294912
  if (t < N0) { msg[t] = f2bf(tree[t]); return; }
  t -= N0;
  if (t < N1) {
    int row = t >> 6, c = t & 63;
    fbpad[t] = (c < 40) ? f2bf(fbonds[row * 40 + c]) : (u16)0;
    return;
  }
  t -= N1;
  if (t < N2) {
    int n = t / 576, k = t - n * 576;
    float v = 0.f;
    if (k < 40) v = Wi[k * 512 + n];
    else if (k >= 64) v = Wh[(k - 64) * 512 + n];
    wcat[t] = f2bf(v);
    return;
  }
  t -= N2;
  if (t < N3) {
    int n = t / 576, k = t - n * 576;
    float v = 0.f;
    if (k < 512) v = Wo[(35 + k) * 512 + n];        // nei part
    else if (k < 547) v = Wo[(k - 512) * 512 + n];  // fatoms part
    wo_t[t] = f2bf(v);
    return;
  }
}

// ---------------- gather-sum: wave per row, XCD-affine row mapping ----------
// r7-verified verbatim (153us, 0 bank conflicts, occupancy 63%).
__global__ __launch_bounds__(256) void gather_bonds(
    const u16* __restrict__ msg, const int* __restrict__ bgraph,
    u16* __restrict__ nei) {
  const int xcd = blockIdx.x & 7;
  const int chunk = blockIdx.x >> 3;
  int row = xcd * (NB / 8) + chunk * 4 + (threadIdx.x >> 6);
  int lane = threadIdx.x & 63;
  const int* idxp = bgraph + row * MAX_NB;
  float acc[8] = {0, 0, 0, 0, 0, 0, 0, 0};
#pragma unroll
  for (int j = 0; j < MAX_NB; j++) {
    int id = idxp[j];
    uint4 v = *(const uint4*)(msg + (size_t)id * HID + lane * 8);
    acc[0] += bflo(v.x); acc[1] += bfhi(v.x);
    acc[2] += bflo(v.y); acc[3] += bfhi(v.y);
    acc[4] += bflo(v.z); acc[5] += bfhi(v.z);
    acc[6] += bflo(v.w); acc[7] += bfhi(v.w);
  }
  uint4 o;
  o.x = (u32)f2bf(acc[0]) | ((u32)f2bf(acc[1]) << 16);
  o.y = (u32)f2bf(acc[2]) | ((u32)f2bf(acc[3]) << 16);
  o.z = (u32)f2bf(acc[4]) | ((u32)f2bf(acc[5]) << 16);
  o.w = (u32)f2bf(acc[6]) | ((u32)f2bf(acc[7]) << 16);
  *(uint4*)(nei + (size_t)row * HID + lane * 8) = o;
}

// atom gather: r7-verified; builds ainput [nei(512) | fatoms(35) | pad(29)]
__global__ __launch_bounds__(256) void gather_atoms(
    const u16* __restrict__ msg, const int* __restrict__ agraph,
    const float* __restrict__ fatoms, u16* __restrict__ ainput) {
  const int xcd = blockIdx.x & 7;
  const int chunk = blockIdx.x >> 3;
  int row = xcd * (NA / 8) + chunk * 4 + (threadIdx.x >> 6);
  int lane = threadIdx.x & 63;
  const int* idxp = agraph + row * MAX_NB;
  float acc[8] = {0, 0, 0, 0, 0, 0, 0, 0};
#pragma unroll
  for (int j = 0; j < MAX_NB; j++) {
    int id = idxp[j];
    uint4 v = *(const uint4*)(msg + (size_t)id * HID + lane * 8);
    acc[0] += bflo(v.x); acc[1] += bfhi(v.x);
    acc[2] += bflo(v.y); acc[3] += bfhi(v.y);
    acc[4] += bflo(v.z); acc[5] += bfhi(v.z);
    acc[6] += bflo(v.w); acc[7] += bfhi(v.w);
  }
  uint4 o;
  o.x = (u32)f2bf(acc[0]) | ((u32)f2bf(acc[1]) << 16);
  o.y = (u32)f2bf(acc[2]) | ((u32)f2bf(acc[3]) << 16);
  o.z = (u32)f2bf(acc[4]) | ((u32)f2bf(acc[5]) << 16);
  o.w = (u32)f2bf(acc[6]) | ((u32)f2bf(acc[7]) << 16);
  u16* arow = ainput + (size_t)row * 576;
  *(uint4*)(arow + lane * 8) = o;
  float tv = (lane < 35) ? fatoms[(size_t)row * 35 + lane] : 0.f;
  arow[512 + lane] = f2bf(tv);
}

// ---------------- 128x128 bf16 MFMA GEMM, XCD-swizzled 1D grid ---------------
// A is split along K: kb < kSplit reads A1 (stride s1), else A2 (stride 512,
// offset kb-kSplit). EPI 0: msg graph part = relu(acc).
// EPI 2: out[mol] = mean(relu(acc+bias)).
template <int EPI>
__global__ __launch_bounds__(256) void gemm_k(
    const u16* __restrict__ A1, int s1, int kSplit,
    const u16* __restrict__ A2, const u16* __restrict__ Bt, int Bstride, int K,
    int mtx, u16* __restrict__ msgout, const float* __restrict__ bo,
    const int* __restrict__ scope, float* __restrict__ out) {
  __shared__ __align__(16) u16 As[128 * 32];
  __shared__ __align__(16) u16 Bs[128 * 32];
  const int L = blockIdx.x;
  const int xcd = L & 7;
  const int q = L >> 3;
  const int mBase = (xcd * mtx + (q >> 2)) * 128;
  const int nBase = (q & 3) * 128;
  const int t = threadIdx.x;
  const int lane = t & 63;
  const int w = t >> 6;
  const int wm = w & 1, wn = w >> 1;
  const int r = t >> 2;
  const int c8 = (t & 3) * 8;
  const int q8 = (lane >> 4) * 8;
  const int l15 = lane & 15;

  f32x4 acc[4][4];
#pragma unroll
  for (int i = 0; i < 4; i++)
#pragma unroll
    for (int j = 0; j < 4; j++)
#pragma unroll
      for (int rg = 0; rg < 4; rg++) acc[i][j][rg] = 0.f;

  for (int kb = 0; kb < K; kb += 32) {
    const u16* Ab;
    int Astr, kOff;
    if (kb < kSplit) { Ab = A1; Astr = s1; kOff = kb; }
    else { Ab = A2; Astr = 512; kOff = kb - kSplit; }
    __syncthreads();
    async16(Ab + (size_t)(mBase + r) * Astr + kOff + c8, As + r * 32 + c8);
    async16(Ab + (size_t)(mBase + r + 64) * Astr + kOff + c8,
            As + (r + 64) * 32 + c8);
    async16(Bt + (size_t)(nBase + r) * Bstride + kb + c8, Bs + r * 32 + c8);
    async16(Bt + (size_t)(nBase + r + 64) * Bstride + kb + c8,
            Bs + (r + 64) * 32 + c8);
    __syncthreads();
    bf16x8 av[4], bv[4];
#pragma unroll
    for (int i = 0; i < 4; i++)
      av[i] = *(const bf16x8*)(As + (wm * 64 + i * 16 + l15) * 32 + q8);
#pragma unroll
    for (int j = 0; j < 4; j++)
      bv[j] = *(const bf16x8*)(Bs + (wn * 64 + j * 16 + l15) * 32 + q8);
#pragma unroll
    for (int i = 0; i < 4; i++)
#pragma unroll
      for (int j = 0; j < 4; j++)
        acc[i][j] = __builtin_amdgcn_mfma_f32_16x16x32_bf16(av[i], bv[j],
                                                            acc[i][j], 0, 0, 0);
  }

  if (EPI == 2) {
#pragma unroll
    for (int m = 0; m < 2; m++) {
      int mol = (mBase + wm * 64 + m * 32) >> 5;
      float inv_le = 1.0f / (float)scope[mol * 2 + 1];
#pragma unroll
      for (int j = 0; j < 4; j++) {
        int col = nBase + wn * 64 + j * 16 + l15;
        float bias = bo[col];
        float s = 0.f;
#pragma unroll
        for (int i = 2 * m; i < 2 * m + 2; i++)
#pragma unroll
          for (int rg = 0; rg < 4; rg++)
            s += fmaxf(acc[i][j][rg] + bias, 0.f);
        s += __shfl_xor(s, 16, 64);
        s += __shfl_xor(s, 32, 64);
        if (lane < 16) out[(size_t)mol * HID + col] = s * inv_le;
      }
    }
  } else {
#pragma unroll
    for (int i = 0; i < 4; i++) {
      int row = mBase + wm * 64 + i * 16 + (lane >> 4) * 4;
#pragma unroll
      for (int j = 0; j < 4; j++) {
        int col = nBase + wn * 64 + j * 16 + l15;
#pragma unroll
        for (int rg = 0; rg < 4; rg++) {
          size_t gi = (size_t)(row + rg) * HID + col;
          msgout[(size_t)NMESS * HID + gi] = f2bf(fmaxf(acc[i][j][rg], 0.f));
        }
      }
    }
  }
}

// ---------------- launch ----------------
extern "C" void kernel_launch(void* const* d_in, const int* in_sizes, int n_in,
                              void* d_out, int out_size, void* d_ws,
                              size_t ws_size, hipStream_t stream) {
  const float* fatoms = (const float*)d_in[0];
  const float* fbonds = (const float*)d_in[1];
  const int* agraph = (const int*)d_in[2];
  const int* bgraph = (const int*)d_in[3];
  const int* scope = (const int*)d_in[4];
  const float* tree = (const float*)d_in[5];
  const float* Wi = (const float*)d_in[6];
  const float* Wh = (const float*)d_in[7];
  const float* Wo = (const float*)d_in[8];
  const float* bo = (const float*)d_in[9];
  float* out = (float*)d_out;

  // layout (152.2 MB, well under the 210.9 MB known-good budget):
  // [msg 75.5MB][nei 67MB][fbpad 8.4MB][wcat 0.59MB][wo_t 0.59MB]
  char* ws = (char*)d_ws;
  u16* msg = (u16*)(ws);
  u16* nei = (u16*)(ws + 75497472ull);
  u16* fbpad = (u16*)(ws + 142606336ull);
  u16* wcat = (u16*)(ws + 150994944ull);
  u16* wo_t = (u16*)(ws + 151584768ull);
  u16* ainput = nei;  // alias: nei dead once gather_atoms runs

  prep_kernel<<<35072, 256, 0, stream>>>(fbonds, tree, Wi, Wh, Wo, msg, fbpad,
                                         wcat, wo_t);

  // init: msg_graph = relu(fbpad @ Wi)  (K=64, first 64 k-cols of wcat)
  gemm_k<0><<<2048, 256, 0, stream>>>(fbpad, 64, 64, nullptr, wcat, 576, 64,
                                      64, msg, nullptr, nullptr, nullptr);
  for (int d = 0; d < 5; d++) {
    gather_bonds<<<NB / 4, 256, 0, stream>>>(msg, bgraph, nei);
    // msg_graph = relu([fbpad | nei] @ wcat), K=576
    gemm_k<0><<<2048, 256, 0, stream>>>(fbpad, 64, 64, nei, wcat, 576, 576,
                                        64, msg, nullptr, nullptr, nullptr);
  }
  gather_atoms<<<NA / 4, 256, 0, stream>>>(msg, agraph, fatoms, ainput);
  // out: mean over molecule of relu(ainput @ Wo + bo), K=576
  gemm_k<2><<<1024, 256, 0, stream>>>(ainput, 576, 576, nullptr, wo_t, 576,
                                      576, 32, nullptr, bo, scope, out);
}

// Round 7
// 1221.200 us; speedup vs baseline: 1.3708x; 1.0178x over previous
//
#include <hip/hip_runtime.h>
#include <stdint.h>

// JTMPN on MI355X — round 14: back to the r10-verified serial skeleton
// (1243us) after the overlap line produced two counter-less failures.
// Two protocol-free changes: (1) gather issues all 15 row-loads into
// registers before accumulating (tests MSHR-cap vs per-wave-ILP wall;
// bit-identical summation order); (2) GEMM k-loop double-buffers LDS with
// prefetch-next-before-compute, one barrier per k-step (T3-minimum).
// Everything else (layouts, epilogues, augmented-K, fbpad) = r10 verbatim.

#define MAX_NB 15
#define HID 512
#define NA 32768
#define NB 65536
#define NMESS 8192

typedef unsigned short u16;
typedef unsigned int u32;
typedef __bf16 bf16x8 __attribute__((ext_vector_type(8)));
typedef float f32x4 __attribute__((ext_vector_type(4)));

__device__ __forceinline__ u16 f2bf(float f) {
  u32 u = __builtin_bit_cast(u32, f);
  u32 r = (u + 0x7fffu + ((u >> 16) & 1u)) >> 16;
  return (u16)r;
}
__device__ __forceinline__ float bflo(u32 u) {
  return __builtin_bit_cast(float, u << 16);
}
__device__ __forceinline__ float bfhi(u32 u) {
  return __builtin_bit_cast(float, u & 0xffff0000u);
}

__device__ __forceinline__ void async16(const u16* g, u16* l) {
  __builtin_amdgcn_global_load_lds(
      (const __attribute__((address_space(1))) u32*)g,
      (__attribute__((address_space(3))) u32*)l, 16, 0, 0);
}

// ---------------- prep: fp32 -> bf16 conversions / transposes ----------------
__global__ __launch_bounds__(256) void prep_kernel(
    const float* __restrict__ fbonds, const float* __restrict__ tree,
    const float* __restrict__ Wi, const float* __restrict__ Wh,
    const float* __restrict__ Wo, u16* __restrict__ msg,
    u16* __restrict__ fbpad, u16* __restrict__ wcat, u16* __restrict__ wo_t) {
  int t = blockIdx.x * 256 + threadIdx.x;
  const int N0 = NMESS * HID;  // 4194304
  const int N1 = NB * 64;      // 4194304
  const int N2 = 512 * 576;    // 294912
  const int N3 = 512 * 576;    // 294912
  if (t < N0) { msg[t] = f2bf(tree[t]); return; }
  t -= N0;
  if (t < N1) {
    int row = t >> 6, c = t & 63;
    fbpad[t] = (c < 40) ? f2bf(fbonds[row * 40 + c]) : (u16)0;
    return;
  }
  t -= N1;
  if (t < N2) {
    int n = t / 576, k = t - n * 576;
    float v = 0.f;
    if (k < 40) v = Wi[k * 512 + n];
    else if (k >= 64) v = Wh[(k - 64) * 512 + n];
    wcat[t] = f2bf(v);
    return;
  }
  t -= N2;
  if (t < N3) {
    int n = t / 576, k = t - n * 576;
    float v = 0.f;
    if (k < 512) v = Wo[(35 + k) * 512 + n];        // nei part
    else if (k < 547) v = Wo[(k - 512) * 512 + n];  // fatoms part
    wo_t[t] = f2bf(v);
    return;
  }
}

// ---------------- gather-sum: wave per row, deep-ILP load batch ----------
// All 15 row-loads issued before any accumulation (3x outstanding misses).
// Per-element summation order (j ascending) identical to r7/r10.
__global__ __launch_bounds__(256) void gather_bonds(
    const u16* __restrict__ msg, const int* __restrict__ bgraph,
    u16* __restrict__ nei) {
  const int xcd = blockIdx.x & 7;
  const int chunk = blockIdx.x >> 3;
  int row = xcd * (NB / 8) + chunk * 4 + (threadIdx.x >> 6);
  int lane = threadIdx.x & 63;
  const int* idxp = bgraph + row * MAX_NB;
  int ids[MAX_NB];
#pragma unroll
  for (int j = 0; j < MAX_NB; j++) ids[j] = idxp[j];
  uint4 v[MAX_NB];
#pragma unroll
  for (int j = 0; j < MAX_NB; j++)
    v[j] = *(const uint4*)(msg + (size_t)ids[j] * HID + lane * 8);
  float acc[8] = {0, 0, 0, 0, 0, 0, 0, 0};
#pragma unroll
  for (int j = 0; j < MAX_NB; j++) {
    acc[0] += bflo(v[j].x); acc[1] += bfhi(v[j].x);
    acc[2] += bflo(v[j].y); acc[3] += bfhi(v[j].y);
    acc[4] += bflo(v[j].z); acc[5] += bfhi(v[j].z);
    acc[6] += bflo(v[j].w); acc[7] += bfhi(v[j].w);
  }
  uint4 o;
  o.x = (u32)f2bf(acc[0]) | ((u32)f2bf(acc[1]) << 16);
  o.y = (u32)f2bf(acc[2]) | ((u32)f2bf(acc[3]) << 16);
  o.z = (u32)f2bf(acc[4]) | ((u32)f2bf(acc[5]) << 16);
  o.w = (u32)f2bf(acc[6]) | ((u32)f2bf(acc[7]) << 16);
  *(uint4*)(nei + (size_t)row * HID + lane * 8) = o;
}

// atom gather: same deep-ILP; builds ainput [nei(512) | fatoms(35) | pad(29)]
__global__ __launch_bounds__(256) void gather_atoms(
    const u16* __restrict__ msg, const int* __restrict__ agraph,
    const float* __restrict__ fatoms, u16* __restrict__ ainput) {
  const int xcd = blockIdx.x & 7;
  const int chunk = blockIdx.x >> 3;
  int row = xcd * (NA / 8) + chunk * 4 + (threadIdx.x >> 6);
  int lane = threadIdx.x & 63;
  const int* idxp = agraph + row * MAX_NB;
  int ids[MAX_NB];
#pragma unroll
  for (int j = 0; j < MAX_NB; j++) ids[j] = idxp[j];
  uint4 v[MAX_NB];
#pragma unroll
  for (int j = 0; j < MAX_NB; j++)
    v[j] = *(const uint4*)(msg + (size_t)ids[j] * HID + lane * 8);
  float acc[8] = {0, 0, 0, 0, 0, 0, 0, 0};
#pragma unroll
  for (int j = 0; j < MAX_NB; j++) {
    acc[0] += bflo(v[j].x); acc[1] += bfhi(v[j].x);
    acc[2] += bflo(v[j].y); acc[3] += bfhi(v[j].y);
    acc[4] += bflo(v[j].z); acc[5] += bfhi(v[j].z);
    acc[6] += bflo(v[j].w); acc[7] += bfhi(v[j].w);
  }
  uint4 o;
  o.x = (u32)f2bf(acc[0]) | ((u32)f2bf(acc[1]) << 16);
  o.y = (u32)f2bf(acc[2]) | ((u32)f2bf(acc[3]) << 16);
  o.z = (u32)f2bf(acc[4]) | ((u32)f2bf(acc[5]) << 16);
  o.w = (u32)f2bf(acc[6]) | ((u32)f2bf(acc[7]) << 16);
  u16* arow = ainput + (size_t)row * 576;
  *(uint4*)(arow + lane * 8) = o;
  float tv = (lane < 35) ? fatoms[(size_t)row * 35 + lane] : 0.f;
  arow[512 + lane] = f2bf(tv);
}

// ---------------- 128x128 bf16 MFMA GEMM, dbuf prefetch, XCD-swizzled -------
// A split along K at kSplit (A1 stride s1, A2 stride 512). LDS double-buffer:
// stage k-tile t+1 into buf^1 before computing tile t; ONE barrier per step.
// Hazard audit: barrier at end of step t-1 guarantees (a) vmcnt drained ->
// buf[cur] fully staged, (b) all waves done reading buf[cur^1] -> safe to
// overwrite it this step. EPI 0: msg=relu(acc). EPI 2: per-molecule mean.
template <int EPI>
__global__ __launch_bounds__(256) void gemm_k(
    const u16* __restrict__ A1, int s1, int kSplit,
    const u16* __restrict__ A2, const u16* __restrict__ Bt, int Bstride, int K,
    int mtx, u16* __restrict__ msgout, const float* __restrict__ bo,
    const int* __restrict__ scope, float* __restrict__ out) {
  __shared__ __align__(16) u16 As[2][128 * 32];
  __shared__ __align__(16) u16 Bs[2][128 * 32];
  const int L = blockIdx.x;
  const int xcd = L & 7;
  const int q = L >> 3;
  const int mBase = (xcd * mtx + (q >> 2)) * 128;
  const int nBase = (q & 3) * 128;
  const int t = threadIdx.x;
  const int lane = t & 63;
  const int w = t >> 6;
  const int wm = w & 1, wn = w >> 1;
  const int r = t >> 2;
  const int c8 = (t & 3) * 8;
  const int q8 = (lane >> 4) * 8;
  const int l15 = lane & 15;

  f32x4 acc[4][4];
#pragma unroll
  for (int i = 0; i < 4; i++)
#pragma unroll
    for (int j = 0; j < 4; j++)
#pragma unroll
      for (int rg = 0; rg < 4; rg++) acc[i][j][rg] = 0.f;

  auto stage = [&](int c, int kb) {
    const u16* Ab;
    int Astr, kOff;
    if (kb < kSplit) { Ab = A1; Astr = s1; kOff = kb; }
    else { Ab = A2; Astr = 512; kOff = kb - kSplit; }
    async16(Ab + (size_t)(mBase + r) * Astr + kOff + c8, As[c] + r * 32 + c8);
    async16(Ab + (size_t)(mBase + r + 64) * Astr + kOff + c8,
            As[c] + (r + 64) * 32 + c8);
    async16(Bt + (size_t)(nBase + r) * Bstride + kb + c8, Bs[c] + r * 32 + c8);
    async16(Bt + (size_t)(nBase + r + 64) * Bstride + kb + c8,
            Bs[c] + (r + 64) * 32 + c8);
  };

  stage(0, 0);
  __syncthreads();  // drains vmcnt: buf0 ready
  int cur = 0;
  for (int kb = 0; kb < K; kb += 32) {
    if (kb + 32 < K) stage(cur ^ 1, kb + 32);  // prefetch next tile
    bf16x8 av[4], bv[4];
#pragma unroll
    for (int i = 0; i < 4; i++)
      av[i] = *(const bf16x8*)(As[cur] + (wm * 64 + i * 16 + l15) * 32 + q8);
#pragma unroll
    for (int j = 0; j < 4; j++)
      bv[j] = *(const bf16x8*)(Bs[cur] + (wn * 64 + j * 16 + l15) * 32 + q8);
#pragma unroll
    for (int i = 0; i < 4; i++)
#pragma unroll
      for (int j = 0; j < 4; j++)
        acc[i][j] = __builtin_amdgcn_mfma_f32_16x16x32_bf16(av[i], bv[j],
                                                            acc[i][j], 0, 0, 0);
    __syncthreads();  // all reads of buf[cur] done + next buf staged
    cur ^= 1;
  }

  if (EPI == 2) {
#pragma unroll
    for (int m = 0; m < 2; m++) {
      int mol = (mBase + wm * 64 + m * 32) >> 5;
      float inv_le = 1.0f / (float)scope[mol * 2 + 1];
#pragma unroll
      for (int j = 0; j < 4; j++) {
        int col = nBase + wn * 64 + j * 16 + l15;
        float bias = bo[col];
        float s = 0.f;
#pragma unroll
        for (int i = 2 * m; i < 2 * m + 2; i++)
#pragma unroll
          for (int rg = 0; rg < 4; rg++)
            s += fmaxf(acc[i][j][rg] + bias, 0.f);
        s += __shfl_xor(s, 16, 64);
        s += __shfl_xor(s, 32, 64);
        if (lane < 16) out[(size_t)mol * HID + col] = s * inv_le;
      }
    }
  } else {
#pragma unroll
    for (int i = 0; i < 4; i++) {
      int row = mBase + wm * 64 + i * 16 + (lane >> 4) * 4;
#pragma unroll
      for (int j = 0; j < 4; j++) {
        int col = nBase + wn * 64 + j * 16 + l15;
#pragma unroll
        for (int rg = 0; rg < 4; rg++) {
          size_t gi = (size_t)(row + rg) * HID + col;
          msgout[(size_t)NMESS * HID + gi] = f2bf(fmaxf(acc[i][j][rg], 0.f));
        }
      }
    }
  }
}

// ---------------- launch ----------------
extern "C" void kernel_launch(void* const* d_in, const int* in_sizes, int n_in,
                              void* d_out, int out_size, void* d_ws,
                              size_t ws_size, hipStream_t stream) {
  const float* fatoms = (const float*)d_in[0];
  const float* fbonds = (const float*)d_in[1];
  const int* agraph = (const int*)d_in[2];
  const int* bgraph = (const int*)d_in[3];
  const int* scope = (const int*)d_in[4];
  const float* tree = (const float*)d_in[5];
  const float* Wi = (const float*)d_in[6];
  const float* Wh = (const float*)d_in[7];
  const float* Wo = (const float*)d_in[8];
  const float* bo = (const float*)d_in[9];
  float* out = (float*)d_out;

  // layout (152.2 MB, = r10 verbatim):
  // [msg 75.5MB][nei 67MB][fbpad 8.4MB][wcat 0.59MB][wo_t 0.59MB]
  char* ws = (char*)d_ws;
  u16* msg = (u16*)(ws);
  u16* nei = (u16*)(ws + 75497472ull);
  u16* fbpad = (u16*)(ws + 142606336ull);
  u16* wcat = (u16*)(ws + 150994944ull);
  u16* wo_t = (u16*)(ws + 151584768ull);
  u16* ainput = nei;  // alias: nei dead once gather_atoms runs

  prep_kernel<<<35072, 256, 0, stream>>>(fbonds, tree, Wi, Wh, Wo, msg, fbpad,
                                         wcat, wo_t);

  // init: msg_graph = relu(fbpad @ Wi)  (K=64, first 64 k-cols of wcat)
  gemm_k<0><<<2048, 256, 0, stream>>>(fbpad, 64, 64, nullptr, wcat, 576, 64,
                                      64, msg, nullptr, nullptr, nullptr);
  for (int d = 0; d < 5; d++) {
    gather_bonds<<<NB / 4, 256, 0, stream>>>(msg, bgraph, nei);
    // msg_graph = relu([fbpad | nei] @ wcat), K=576
    gemm_k<0><<<2048, 256, 0, stream>>>(fbpad, 64, 64, nei, wcat, 576, 576,
                                        64, msg, nullptr, nullptr, nullptr);
  }
  gather_atoms<<<NA / 4, 256, 0, stream>>>(msg, agraph, fatoms, ainput);
  // out: mean over molecule of relu(ainput @ Wo + bo), K=576
  gemm_k<2><<<1024, 256, 0, stream>>>(ainput, 576, 576, nullptr, wo_t, 576,
                                      576, 32, nullptr, bo, scope, out);
}